// Round 1
// 762.594 us; speedup vs baseline: 1.0600x; 1.0600x over previous
//
#include <hip/hip_runtime.h>

#define BATCH 256
#define DIM   2048
#define NMEM  65536
#define NCLUS 8192
#define TEMP  0.05f

typedef __attribute__((ext_vector_type(8))) short bf16x8;
typedef __attribute__((ext_vector_type(4))) float f32x4;
typedef __attribute__((ext_vector_type(8))) unsigned short u16x8;

#define GLDS(srcp, dstp) __builtin_amdgcn_global_load_lds( \
    (const __attribute__((address_space(1))) void*)(srcp), \
    (__attribute__((address_space(3))) void*)(dstp), 16, 0, 0)

__device__ inline unsigned short f2bf(float f) {
    unsigned u = __float_as_uint(f);
    u += 0x7fffu + ((u >> 16) & 1u);   // RNE
    return (unsigned short)(u >> 16);
}

// --- counts per cluster + targets gather + inputs fp32->bf16 (pre-swizzled) --
// A_sw layout: [k/32][b][slot^= (b&3)][k&7]  (slot = (k>>3)&3), so that a linear
// global_load_lds copy lands bank-swizzled in LDS (rule 21: swizzle at source).
__global__ void k_init(const int* __restrict__ labels, const int* __restrict__ indexes,
                       const float* __restrict__ inputs,
                       int* __restrict__ nums, int* __restrict__ targets,
                       unsigned short* __restrict__ A_sw) {
    int gid = blockIdx.x * 256 + threadIdx.x;      // 65536 threads
    atomicAdd(&nums[labels[gid]], 1);
    if (gid < BATCH) targets[gid] = labels[indexes[gid]];
    int e = gid * 8;
    int r = e >> 11;
    int k = e & 2047;
    const float4* p = (const float4*)(inputs + (size_t)r * DIM + k);
    float4 f0 = p[0], f1 = p[1];
    u16x8 o;
    o[0] = f2bf(f0.x); o[1] = f2bf(f0.y); o[2] = f2bf(f0.z); o[3] = f2bf(f0.w);
    o[4] = f2bf(f1.x); o[5] = f2bf(f1.y); o[6] = f2bf(f1.z); o[7] = f2bf(f1.w);
    int slot = ((k >> 3) & 3) ^ (r & 3);
    *(u16x8*)(A_sw + (size_t)(k >> 5) * (BATCH * 32) + r * 32 + slot * 8) = o;
}

// --- exclusive prefix over NCLUS counts (1 block, 256 thr x 32 each) ---------
__global__ void k_scan(const int* __restrict__ nums, int* __restrict__ offs) {
    __shared__ int part[256];
    int t = threadIdx.x;
    int base = t * 32;
    int local[32];
    int s = 0;
    #pragma unroll
    for (int i = 0; i < 32; i++) { local[i] = s; s += nums[base + i]; }
    part[t] = s;
    __syncthreads();
    for (int d = 1; d < 256; d <<= 1) {
        int v = (t >= d) ? part[t - d] : 0;
        __syncthreads();
        part[t] += v;
        __syncthreads();
    }
    int cb = (t == 0) ? 0 : part[t - 1];
    #pragma unroll
    for (int i = 0; i < 32; i++) offs[base + i] = cb + local[i];
}

// --- scatter member indices per cluster --------------------------------------
__global__ void k_scatter(const int* __restrict__ labels, const int* __restrict__ offs,
                          int* __restrict__ cursor, int* __restrict__ order) {
    int n = blockIdx.x * 256 + threadIdx.x;
    int c = labels[n];
    int pos = atomicAdd(&cursor[c], 1);
    order[offs[c] + pos] = n;
}

// --- cluster-sum of feature rows: csum[c] = sum features[n], bf16 out --------
// one block per cluster; nontemporal loads: 512 MB stream with zero reuse.
__global__ __launch_bounds__(256) void k_agg(const float* __restrict__ feats,
                                             const int* __restrict__ order,
                                             const int* __restrict__ offs,
                                             const int* __restrict__ nums,
                                             unsigned short* __restrict__ csum) {
    int c = blockIdx.x;
    int t = threadIdx.x;
    int cnt = nums[c], off = offs[c];
    float acc[8] = {0.f, 0.f, 0.f, 0.f, 0.f, 0.f, 0.f, 0.f};
    int nn = (cnt > 0) ? order[off] : 0;
    for (int i = 0; i < cnt; i++) {
        int ncur = nn;
        if (i + 1 < cnt) nn = order[off + i + 1];
        const f32x4* p = (const f32x4*)(feats + (size_t)ncur * DIM + t * 8);
        f32x4 a = __builtin_nontemporal_load(p);
        f32x4 b = __builtin_nontemporal_load(p + 1);
        acc[0] += a[0]; acc[1] += a[1]; acc[2] += a[2]; acc[3] += a[3];
        acc[4] += b[0]; acc[5] += b[1]; acc[6] += b[2]; acc[7] += b[3];
    }
    u16x8 o;
    #pragma unroll
    for (int j = 0; j < 8; j++) o[j] = f2bf(acc[j]);
    *(u16x8*)(csum + (size_t)c * DIM + t * 8) = o;
}

// --- diag: wave-per-member, shuffle reduce (no barriers in the loop) ---------
__global__ void k_diag(const float* __restrict__ inputs, const float* __restrict__ feats,
                       const int* __restrict__ order, const int* __restrict__ offs,
                       const int* __restrict__ nums, const int* __restrict__ targets,
                       float* __restrict__ numval) {
    int b = blockIdx.x;
    int tid = threadIdx.x;
    int w = tid >> 6, l = tid & 63;
    int c = targets[b];
    int cnt = nums[c], off = offs[c];
    const float4* ip = (const float4*)(inputs + (size_t)b * DIM);
    float4 x[8];
    #pragma unroll
    for (int p = 0; p < 4; p++) {
        x[2 * p]     = ip[p * 128 + l * 2];
        x[2 * p + 1] = ip[p * 128 + l * 2 + 1];
    }
    float d2 = 0.f;
    for (int i = w; i < cnt; i += 4) {
        int n = order[off + i];
        const float4* fp = (const float4*)(feats + (size_t)n * DIM);
        float dot = 0.f;
        #pragma unroll
        for (int p = 0; p < 4; p++) {
            float4 f0 = fp[p * 128 + l * 2];
            float4 f1 = fp[p * 128 + l * 2 + 1];
            dot += x[2*p].x * f0.x + x[2*p].y * f0.y + x[2*p].z * f0.z + x[2*p].w * f0.w
                 + x[2*p+1].x * f1.x + x[2*p+1].y * f1.y + x[2*p+1].z * f1.z + x[2*p+1].w * f1.w;
        }
        #pragma unroll
        for (int m = 32; m >= 1; m >>= 1) dot += __shfl_xor(dot, m, 64);
        d2 += dot * dot;
    }
    __shared__ float red[4];
    if (l == 0) red[w] = d2;
    __syncthreads();
    if (tid == 0) numval[b] = __expf((red[0] + red[1] + red[2] + red[3]) * (1.f / TEMP));
}

// --- fused GEMM + softmax-denominator ----------------------------------------
// BM=256 (full batch), BN=32, BK=32, full K=2048 (64 steps); 4 waves x (64M x 32N).
// Counted-vmcnt double-buffered pipeline (raw s_barrier, no vmcnt(0) drain in loop).
// Epilogue: cnt/cmask/target-mask + exp in-register, shuffle-reduce over clusters,
// atomicAdd into denom[b]. No simP intermediate.
__global__ __launch_bounds__(256) void k_gemm(const unsigned short* __restrict__ csum,
                                              const unsigned short* __restrict__ A_sw,
                                              const int* __restrict__ nums,
                                              const int* __restrict__ targets,
                                              float* __restrict__ denom) {
    __shared__ short As[2][BATCH * 32];   // 2 x 16 KB, rows of 64 B, slot^= (row&3)
    __shared__ short Bs[2][32 * 64];      // 2 x 4 KB, rows of 128 B (k-pair), slot^= (row&7)
    __shared__ int   s_tgt[BATCH];
    int tid = threadIdx.x;
    int w = tid >> 6, l = tid & 63;
    int n0 = blockIdx.x * 32;
    int ar = l & 15, aq = l >> 4;

    s_tgt[tid] = targets[tid];

    // B staging source: wave w stages rows w*8..w*8+7; global col-group is
    // pre-permuted so the linear LDS landing is the swizzled layout.
    int br = w * 8 + (l >> 3);
    int bg = (l & 7) ^ (l >> 3);
    const char* bsrc = (const char*)(csum + (size_t)(n0 + br) * DIM + bg * 8);

    // prologue: stage A chunk 0 (identity copy; swizzle baked into A_sw) + B pair 0
    {
        const char* g = (const char*)A_sw;
        #pragma unroll
        for (int i = 0; i < 4; i++) {
            int ofs = w * 4096 + i * 1024;
            GLDS(g + ofs + l * 16, (char*)&As[0][0] + ofs);
        }
        GLDS(bsrc, (char*)&Bs[0][0] + w * 1024);
    }

    f32x4 acc[4][2];
    #pragma unroll
    for (int i = 0; i < 4; i++) {
        acc[i][0] = (f32x4){0.f, 0.f, 0.f, 0.f};
        acc[i][1] = (f32x4){0.f, 0.f, 0.f, 0.f};
    }
    __syncthreads();   // drains prologue loads + publishes s_tgt (once)

    for (int ks = 0; ks < 64; ks++) {
        int cab = ks & 1;
        int cbb = (ks >> 1) & 1;
        // issue prefetch (stays in flight across the barriers)
        if (ks + 1 < 64) {
            const char* g = (const char*)A_sw + (size_t)(ks + 1) * 16384;
            #pragma unroll
            for (int i = 0; i < 4; i++) {
                int ofs = w * 4096 + i * 1024;
                GLDS(g + ofs + l * 16, (char*)&As[cab ^ 1][0] + ofs);
            }
        }
        if (((ks & 1) == 0) && ks + 2 < 64) {
            GLDS(bsrc + (size_t)(ks + 2) * 64, (char*)&Bs[cbb ^ 1][0] + w * 1024);
        }
        // wait only for loads older than this iteration's issues = current buffers
        if (ks == 63)                        asm volatile("s_waitcnt vmcnt(0)" ::: "memory");
        else if (((ks & 1) == 0) && ks < 62) asm volatile("s_waitcnt vmcnt(5)" ::: "memory");
        else                                 asm volatile("s_waitcnt vmcnt(4)" ::: "memory");
        __builtin_amdgcn_s_barrier();

        const short* Ab = &As[cab][0];
        const short* Bb = &Bs[cbb][0];
        int gsb = (ks & 1) * 4;
        bf16x8 a[4], b[2];
        #pragma unroll
        for (int i = 0; i < 4; i++)
            a[i] = *(const bf16x8*)&Ab[(w * 64 + i * 16 + ar) * 32 + ((aq ^ (ar & 3)) * 8)];
        #pragma unroll
        for (int j = 0; j < 2; j++)
            b[j] = *(const bf16x8*)&Bb[(j * 16 + ar) * 64 + (((gsb + aq) ^ (ar & 7)) * 8)];
        #pragma unroll
        for (int i = 0; i < 4; i++) {
            acc[i][0] = __builtin_amdgcn_mfma_f32_16x16x32_bf16(a[i], b[0], acc[i][0], 0, 0, 0);
            acc[i][1] = __builtin_amdgcn_mfma_f32_16x16x32_bf16(a[i], b[1], acc[i][1], 0, 0, 0);
        }
        __builtin_amdgcn_s_barrier();   // reads done before next iter overwrites
    }

    // --- fused epilogue ------------------------------------------------------
    int c0 = n0 + ar, c1 = n0 + 16 + ar;
    int cnt0 = nums[c0], cnt1 = nums[c1];
    float sc0 = (float)cnt0 * TEMP, sc1 = (float)cnt1 * TEMP;
    float rs[16];
    #pragma unroll
    for (int i = 0; i < 4; i++) {
        #pragma unroll
        for (int r = 0; r < 4; r++) {
            int bi = w * 64 + i * 16 + aq * 4 + r;
            int tg = s_tgt[bi];
            float v = 0.f;
            if (cnt0 > 0 && tg != c0) v += __expf(acc[i][0][r] / sc0);
            if (cnt1 > 0 && tg != c1) v += __expf(acc[i][1][r] / sc1);
            #pragma unroll
            for (int m = 1; m < 16; m <<= 1) v += __shfl_xor(v, m, 64);
            rs[i * 4 + r] = v;   // sum over this block's 32 clusters for row bi
        }
    }
    // lane (ar=m, aq) owns row w*64 + (m>>2)*16 + aq*4 + (m&3): 64 distinct rows/wave
    float myv = 0.f;
    #pragma unroll
    for (int t = 0; t < 16; t++) if (ar == t) myv = rs[t];
    atomicAdd(&denom[w * 64 + (ar >> 2) * 16 + aq * 4 + (ar & 3)], myv);
}

// --- final loss --------------------------------------------------------------
__global__ void k_loss(const float* __restrict__ denom, const float* __restrict__ numval,
                       float* __restrict__ out) {
    __shared__ float red[256];
    int t = threadIdx.x;
    float nv = numval[t];
    float tot = denom[t] + nv;     // own-cluster term added here
    float ls = -logf(nv / (tot + 1e-6f) + 1e-6f);
    red[t] = ls;
    __syncthreads();
    for (int d = 128; d > 0; d >>= 1) {
        if (t < d) red[t] += red[t + d];
        __syncthreads();
    }
    if (t == 0) out[0] = red[0] / (float)BATCH;
}

extern "C" void kernel_launch(void* const* d_in, const int* in_sizes, int n_in,
                              void* d_out, int out_size, void* d_ws, size_t ws_size,
                              hipStream_t stream) {
    const float* inputs  = (const float*)d_in[0];   // [256, 2048]
    const int*   indexes = (const int*)d_in[1];     // [256]
    const float* feats   = (const float*)d_in[2];   // [65536, 2048]
    const int*   labels  = (const int*)d_in[3];     // [65536]
    float* out = (float*)d_out;

    char* ws = (char*)d_ws;
    size_t off = 0;
    unsigned short* csum = (unsigned short*)(ws + off); off += (size_t)NCLUS * DIM * 2;  // 32 MB
    unsigned short* A_sw = (unsigned short*)(ws + off); off += (size_t)BATCH * DIM * 2;  // 1 MB
    int*   nums    = (int*)(ws + off);   off += NCLUS * 4;
    int*   cursor  = (int*)(ws + off);   off += NCLUS * 4;
    float* denom   = (float*)(ws + off); off += BATCH * 4;     // contiguous with nums/cursor
    int*   offs    = (int*)(ws + off);   off += NCLUS * 4;
    int*   order   = (int*)(ws + off);   off += (size_t)NMEM * 4;
    int*   targets = (int*)(ws + off);   off += BATCH * 4;
    float* numval  = (float*)(ws + off); off += BATCH * 4;

    hipMemsetAsync(nums, 0, NCLUS * 4 + NCLUS * 4 + BATCH * 4, stream);  // nums+cursor+denom

    k_init   <<<NMEM / 256, 256, 0, stream>>>(labels, indexes, inputs, nums, targets, A_sw);
    k_scan   <<<1, 256, 0, stream>>>(nums, offs);
    k_scatter<<<NMEM / 256, 256, 0, stream>>>(labels, offs, cursor, order);
    k_agg    <<<NCLUS, 256, 0, stream>>>(feats, order, offs, nums, csum);
    k_diag   <<<BATCH, 256, 0, stream>>>(inputs, feats, order, offs, nums, targets, numval);
    k_gemm   <<<NCLUS / 32, 256, 0, stream>>>(csum, A_sw, nums, targets, denom);
    k_loss   <<<1, 256, 0, stream>>>(denom, numval, out);
}